// Round 1
// baseline (196.830 us; speedup 1.0000x reference)
//
#include <hip/hip_runtime.h>

namespace {

constexpr int IC = 32;
constexpr int OC = 64;
constexpr int N  = 64;
constexpr int LDS_STRIDE = 72;   // floats: rows stay 16B-aligned; 4*72 % 32 == 0 keeps banks uniform

// out[b,oc,y,x] = sum_ic | sum_{a,b=0..6} kf[a][b] * img[(y-2+a)%64][(x-2+b)%64] |
// with kf[a][b] = ker[6-a][6-b]  (flip from the +4 shift of ifftshift/fftshift algebra)
//
// LDS tile: H[yy][xx] = img[(yy-2)%64][(xx-4)%64], yy in [0,70), xx in [2,72)
//   => img[y-2+a][x-2+b] = H[y+a][x+b+2]
__global__ __launch_bounds__(256, 2) void optconv_abs_sum(
    const float* __restrict__ img,   // [8][32][64][64]
    const float* __restrict__ ker,   // [64][32][7][7]
    float* __restrict__ out)         // [8][64][64][64]
{
    __shared__ float H[70 * LDS_STRIDE];

    const int bid = blockIdx.x;
    const int b   = bid >> 6;
    const int oc  = bid & 63;
    const int tid = threadIdx.x;

    const int x0 = (tid & 15) * 4;   // 16 tiles across
    const int y0 = (tid >> 4) * 4;   // 16 tiles down

    float sum[4][4];
#pragma unroll
    for (int i = 0; i < 4; ++i)
#pragma unroll
        for (int j = 0; j < 4; ++j) sum[i][j] = 0.0f;

    const float* imgB = img + (size_t)b * IC * N * N;
    const float* kerO = ker + (size_t)oc * IC * 49;

    for (int ic = 0; ic < IC; ++ic) {
        const float* src = imgB + ic * N * N;

        __syncthreads();   // previous iteration's reads of H are done

        // ---- stage interior: H[yy][4..67] = img[(yy-2)%64][0..63], float4 ----
        for (int f = tid; f < 70 * 16; f += 256) {
            int yy = f >> 4;
            int c4 = (f & 15) * 4;
            int sy = yy - 2;
            if (sy < 0)  sy += 64;
            if (sy >= 64) sy -= 64;
            const float4 v = *(const float4*)(src + sy * 64 + c4);
            *(float4*)(&H[yy * LDS_STRIDE + 4 + c4]) = v;
        }
        // ---- halo cols xx in {2,3,68,69,70,71} -> img cols {62,63,0,1,2,3} ----
        for (int f = tid; f < 70 * 8; f += 256) {
            int yy = f >> 3;
            int h  = f & 7;
            if (h < 6) {
                int xx = (h < 2) ? (h + 2)  : (h + 66);
                int sc = (h < 2) ? (h + 62) : (h - 2);
                int sy = yy - 2;
                if (sy < 0)  sy += 64;
                if (sy >= 64) sy -= 64;
                H[yy * LDS_STRIDE + xx] = src[sy * 64 + sc];
            }
        }
        __syncthreads();

        // ---- wave-uniform kernel taps (flipped) -> scalar loads ----
        float kreg[49];
#pragma unroll
        for (int t = 0; t < 49; ++t) kreg[t] = kerO[ic * 49 + 48 - t];

        float acc[4][4];
#pragma unroll
        for (int i = 0; i < 4; ++i)
#pragma unroll
            for (int j = 0; j < 4; ++j) acc[i][j] = 0.0f;

        // window rows r = 0..9 (H rows y0..y0+9), 12-wide window per row
#pragma unroll
        for (int r = 0; r < 10; ++r) {
            const float* row = &H[(y0 + r) * LDS_STRIDE + x0];
            const float4 wa = *(const float4*)(row);
            const float4 wb = *(const float4*)(row + 4);
            const float4 wc = *(const float4*)(row + 8);
            const float w[12] = {wa.x, wa.y, wa.z, wa.w,
                                 wb.x, wb.y, wb.z, wb.w,
                                 wc.x, wc.y, wc.z, wc.w};
#pragma unroll
            for (int a = 0; a < 7; ++a) {
                const int yd = r - a;          // output row within tile
                if (yd < 0 || yd > 3) continue;
#pragma unroll
                for (int q = 0; q < 7; ++q) {
                    const float k = kreg[a * 7 + q];
#pragma unroll
                    for (int xi = 0; xi < 4; ++xi)
                        acc[yd][xi] += k * w[xi + q + 2];
                }
            }
        }

#pragma unroll
        for (int i = 0; i < 4; ++i)
#pragma unroll
            for (int j = 0; j < 4; ++j) sum[i][j] += fabsf(acc[i][j]);
    }

    float* o = out + (((size_t)b * OC + oc) * N + y0) * N + x0;
#pragma unroll
    for (int i = 0; i < 4; ++i)
        *(float4*)(o + (size_t)i * N) = make_float4(sum[i][0], sum[i][1], sum[i][2], sum[i][3]);
}

} // namespace

extern "C" void kernel_launch(void* const* d_in, const int* in_sizes, int n_in,
                              void* d_out, int out_size, void* d_ws, size_t ws_size,
                              hipStream_t stream) {
    const float* img = (const float*)d_in[0];   // [8][32][64][64]
    const float* ker = (const float*)d_in[1];   // [64][32][7][7]
    float* out = (float*)d_out;                 // [8][64][64][64]
    optconv_abs_sum<<<dim3(8 * 64), dim3(256), 0, stream>>>(img, ker, out);
}